// Round 4
// baseline (438.391 us; speedup 1.0000x reference)
//
#include <hip/hip_runtime.h>
#include <cfloat>
#include <cmath>
#include <cstdint>

#define N_NODES 128
#define F_IN    256
#define HDIM    512
#define NEDGE   524288

typedef _Float16 half8 __attribute__((ext_vector_type(8)));
typedef _Float16 half4 __attribute__((ext_vector_type(4)));
typedef float f32x4 __attribute__((ext_vector_type(4)));

// ---------------------------------------------------------------------------
// PREP (fused): blocks [0,256) build adjacency bitmask; blocks [256,384)
// convert W2 f32 [k][n] -> f16 transposed [n][k] for both layers.
// ---------------------------------------------------------------------------
__global__ __launch_bounds__(256) void prep_kernel(
    const int* __restrict__ ei, unsigned int* __restrict__ mask,
    const float* __restrict__ W2a, const float* __restrict__ W2b,
    _Float16* __restrict__ Ta, _Float16* __restrict__ Tb) {
  __shared__ __align__(16) char smem[64 * 72 * 2];  // 9216 B union
  const int t = threadIdx.x;
  if (blockIdx.x < 256) {
    // ---- mask part ----
    unsigned int* lm = (unsigned int*)smem;
    for (int i = t; i < N_NODES * 4; i += 256) lm[i] = 0u;
    __syncthreads();
    const int base = blockIdx.x * 2048;
#pragma unroll
    for (int r = 0; r < 8; ++r) {
      const int e = base + r * 256 + t;
      const int s = ei[e];          // src  (x_j)
      const int d = ei[NEDGE + e];  // dst  (segment target)
      atomicOr(&lm[d * 4 + (s >> 5)], 1u << (s & 31));
    }
    __syncthreads();
    for (int i = t; i < N_NODES * 4; i += 256) {
      const unsigned int v = lm[i];
      if (v) atomicOr(&mask[i], v);
    }
  } else {
    // ---- W2 convert+transpose part ----
    const int b = blockIdx.x - 256;       // 0..127
    const int layer = b >> 6;
    const int rem = b & 63;
    const int kb = (rem & 7) * 64;
    const int nb = (rem >> 3) * 64;
    const float* W = layer ? W2b : W2a;
    _Float16* T = layer ? Tb : Ta;
    _Float16(*tile)[72] = (_Float16(*)[72])smem;
#pragma unroll
    for (int i = 0; i < 4; ++i) {
      const int slot = t + i * 256;  // 1024 = 64 kk x 16 nq
      const int kk = slot >> 4;
      const int nq = (slot & 15) * 4;
      const float4 w4 = *reinterpret_cast<const float4*>(
          &W[(size_t)(kb + kk) * HDIM + nb + nq]);
      tile[nq + 0][kk] = (_Float16)w4.x;
      tile[nq + 1][kk] = (_Float16)w4.y;
      tile[nq + 2][kk] = (_Float16)w4.z;
      tile[nq + 3][kk] = (_Float16)w4.w;
    }
    __syncthreads();
#pragma unroll
    for (int i = 0; i < 2; ++i) {
      const int slot = t + i * 256;  // 512 = 64 n x 8 ko
      const int n = slot >> 3;
      const int ko = (slot & 7) * 8;
      *reinterpret_cast<half8*>(&T[(size_t)(nb + n) * HDIM + kb + ko]) =
          *reinterpret_cast<const half8*>(&tile[n][ko]);
    }
  }
}

// ---------------------------------------------------------------------------
// K1/K3: U[d,h] = A[d]@(Wtop-Wbot)[.,h]+b[h], V[d,h] = A[d]@Wbot[.,h]
// Grid (16 h-tiles of 32, 8 K-slices) = 128 blocks; atomicAdd into zeroed U/V.
// ---------------------------------------------------------------------------
template <int KK>
__global__ __launch_bounds__(256) void uv_gemm3_kernel(
    const float* __restrict__ A, const float* __restrict__ W,
    const float* __restrict__ bias, float* __restrict__ U,
    float* __restrict__ V) {
  constexpr int S = 8;
  constexpr int KS = KK / S;
  constexpr int BK = 32;
  __shared__ float As[128][BK + 1];
  __shared__ float Wd[BK][36];
  __shared__ float Wb[BK][36];
  const int t = threadIdx.x;
  const int tx = t & 7;
  const int ty = t >> 3;
  const int h0 = blockIdx.x * 32;
  const int ks0 = blockIdx.y * KS;

  float accU[4][4], accV[4][4];
#pragma unroll
  for (int i = 0; i < 4; ++i)
#pragma unroll
    for (int j = 0; j < 4; ++j) { accU[i][j] = 0.f; accV[i][j] = 0.f; }

  for (int ch = 0; ch < KS / BK; ++ch) {
    const int k0 = ks0 + ch * BK;
    __syncthreads();
#pragma unroll
    for (int i = 0; i < 4; ++i) {
      const int slot = t + i * 256;
      const int dd = slot >> 3, kw = (slot & 7) * 4;
      const float4 a4 =
          *reinterpret_cast<const float4*>(&A[dd * KK + k0 + kw]);
      As[dd][kw + 0] = a4.x;
      As[dd][kw + 1] = a4.y;
      As[dd][kw + 2] = a4.z;
      As[dd][kw + 3] = a4.w;
    }
    {
      const int k = t >> 3, hq = (t & 7) * 4;
      const float4 wt = *reinterpret_cast<const float4*>(
          &W[(size_t)(k0 + k) * HDIM + h0 + hq]);
      const float4 wb = *reinterpret_cast<const float4*>(
          &W[(size_t)(KK + k0 + k) * HDIM + h0 + hq]);
      *reinterpret_cast<float4*>(&Wb[k][hq]) = wb;
      float4 wd;
      wd.x = wt.x - wb.x; wd.y = wt.y - wb.y;
      wd.z = wt.z - wb.z; wd.w = wt.w - wb.w;
      *reinterpret_cast<float4*>(&Wd[k][hq]) = wd;
    }
    __syncthreads();
#pragma unroll
    for (int k = 0; k < BK; ++k) {
      float a[4];
#pragma unroll
      for (int i = 0; i < 4; ++i) a[i] = As[ty * 4 + i][k];
      const float4 wd4 = *reinterpret_cast<const float4*>(&Wd[k][tx * 4]);
      const float4 wb4 = *reinterpret_cast<const float4*>(&Wb[k][tx * 4]);
      const float wdv[4] = {wd4.x, wd4.y, wd4.z, wd4.w};
      const float wbv[4] = {wb4.x, wb4.y, wb4.z, wb4.w};
#pragma unroll
      for (int i = 0; i < 4; ++i)
#pragma unroll
        for (int j = 0; j < 4; ++j) {
          accU[i][j] = fmaf(a[i], wdv[j], accU[i][j]);
          accV[i][j] = fmaf(a[i], wbv[j], accV[i][j]);
        }
    }
  }
  const int cbase = h0 + tx * 4;
  float bb[4] = {0.f, 0.f, 0.f, 0.f};
  if (blockIdx.y == 0) {
#pragma unroll
    for (int j = 0; j < 4; ++j) bb[j] = bias[cbase + j];
  }
#pragma unroll
  for (int i = 0; i < 4; ++i) {
    const int row = ty * 4 + i;
#pragma unroll
    for (int j = 0; j < 4; ++j) {
      atomicAdd(&U[row * HDIM + cbase + j], accU[i][j] + bb[j]);
      atomicAdd(&V[row * HDIM + cbase + j], accV[i][j]);
    }
  }
}

// ---------------------------------------------------------------------------
// K2/K4 v3: MFMA fp16 pair GEMM + fused masked max + bias + relu.
// Block = (d, 128-col tile); grid (4,128)=512. 4 waves; wave owns 32 cols.
// LDS ~41 KB -> 3 blocks/CU; launch_bounds(256,3) caps VGPR for occupancy.
// MFMA 16x16x32_f16: A[m=lane&15][k=quad*8+j]; C/D col=lane&15,row=quad*4+reg.
// ---------------------------------------------------------------------------
#define PBK 64
__global__ __launch_bounds__(256, 3) void pair_mfma_kernel(
    const float* __restrict__ U, const float* __restrict__ V,
    const _Float16* __restrict__ W2t, const float* __restrict__ b2,
    const unsigned int* __restrict__ mask, float* __restrict__ out) {
  __shared__ _Float16 As[128][PBK + 8];  // 18.4 KB
  __shared__ _Float16 Bs[128][PBK + 8];  // 18.4 KB
  __shared__ float Ur[HDIM];             // 2 KB
  __shared__ float red[4][128];          // 2 KB
  const int t = threadIdx.x;
  const int d = blockIdx.y;
  const int c0 = blockIdx.x * 128;
  const int lane = t & 63;
  const int wid = t >> 6;
  const int l15 = lane & 15;
  const int quad = lane >> 4;

  for (int i = t; i < HDIM; i += 256) Ur[i] = U[d * HDIM + i];
  const unsigned int mwv[4] = {mask[d * 4 + 0], mask[d * 4 + 1],
                               mask[d * 4 + 2], mask[d * 4 + 3]};

  f32x4 acc[8][2];
#pragma unroll
  for (int mt = 0; mt < 8; ++mt)
#pragma unroll
    for (int nt = 0; nt < 2; ++nt) acc[mt][nt] = (f32x4)(0.f);

  for (int ch = 0; ch < HDIM / PBK; ++ch) {
    const int k0 = ch * PBK;
    __syncthreads();
    // Stage A: relu(U+V) -> f16, 128 s x 64 k (2048 float4, 8/thread)
#pragma unroll
    for (int i = 0; i < 8; ++i) {
      const int slot = t + i * 256;
      const int s = slot >> 4;
      const int kq = (slot & 15) * 4;
      const float4 v4 =
          *reinterpret_cast<const float4*>(&V[s * HDIM + k0 + kq]);
      const float4 u4 = *reinterpret_cast<const float4*>(&Ur[k0 + kq]);
      half4 h;
      h.x = (_Float16)fmaxf(u4.x + v4.x, 0.f);
      h.y = (_Float16)fmaxf(u4.y + v4.y, 0.f);
      h.z = (_Float16)fmaxf(u4.z + v4.z, 0.f);
      h.w = (_Float16)fmaxf(u4.w + v4.w, 0.f);
      *reinterpret_cast<half4*>(&As[s][kq]) = h;
    }
    // Stage B: W2t rows [c0..c0+128), 64 k f16 (1024 half8, 4/thread)
#pragma unroll
    for (int i = 0; i < 4; ++i) {
      const int slot = t + i * 256;
      const int n = slot >> 3;
      const int ko = (slot & 7) * 8;
      *reinterpret_cast<half8*>(&Bs[n][ko]) = *reinterpret_cast<const half8*>(
          &W2t[(size_t)(c0 + n) * HDIM + k0 + ko]);
    }
    __syncthreads();
#pragma unroll
    for (int ks = 0; ks < PBK / 32; ++ks) {
      half8 bf[2];
#pragma unroll
      for (int nt = 0; nt < 2; ++nt)
        bf[nt] = *reinterpret_cast<const half8*>(
            &Bs[wid * 32 + nt * 16 + l15][ks * 32 + quad * 8]);
#pragma unroll
      for (int mt = 0; mt < 8; ++mt) {
        const half8 af = *reinterpret_cast<const half8*>(
            &As[mt * 16 + l15][ks * 32 + quad * 8]);
#pragma unroll
        for (int nt = 0; nt < 2; ++nt)
          acc[mt][nt] = __builtin_amdgcn_mfma_f32_16x16x32_f16(
              af, bf[nt], acc[mt][nt], 0, 0, 0);
      }
    }
  }
  __syncthreads();
  // Epilogue: masked max over s (m-dim), then +b2, relu.
#pragma unroll
  for (int nt = 0; nt < 2; ++nt) {
    float pm = -FLT_MAX;
#pragma unroll
    for (int mt = 0; mt < 8; ++mt) {
      const int sbase = mt * 16 + quad * 4;
      const unsigned int w = mwv[sbase >> 5] >> (sbase & 31);
#pragma unroll
      for (int r = 0; r < 4; ++r)
        if ((w >> r) & 1u) pm = fmaxf(pm, acc[mt][nt][r]);
    }
    red[quad][wid * 32 + nt * 16 + l15] = pm;
  }
  __syncthreads();
  if (t < 128) {
    const float m = fmaxf(fmaxf(red[0][t], red[1][t]),
                          fmaxf(red[2][t], red[3][t]));
    out[d * HDIM + c0 + t] = fmaxf(m + b2[c0 + t], 0.f);
  }
}

// ---------------------------------------------------------------------------
// K5 v3: z0[j] += sum_i v[i]*W[i,j]. Grid 1024 (64 rows each). Explicit
// 16-deep register load batches force outstanding loads (old version had
// VGPR=28 -> ~1 load in flight -> 766 GB/s).
// ---------------------------------------------------------------------------
__global__ __launch_bounds__(256) void head_gemv_kernel(
    const float* __restrict__ v, const float* __restrict__ W,
    float* __restrict__ z0) {
  __shared__ float vs[64];
  __shared__ float4 red[128];
  const int t = threadIdx.x;
  const int bi = blockIdx.x;
  const int row0 = bi * 64;
  if (t < 64) vs[t] = v[row0 + t];
  __syncthreads();
  const int c4 = (t & 127) * 4;
  const int half = t >> 7;       // rows [half*32, half*32+32)
  const int rbase = half * 32;
  float4 acc = make_float4(0.f, 0.f, 0.f, 0.f);
#pragma unroll
  for (int b = 0; b < 2; ++b) {
    float4 w[16];
#pragma unroll
    for (int i = 0; i < 16; ++i)
      w[i] = *reinterpret_cast<const float4*>(
          &W[(size_t)(row0 + rbase + b * 16 + i) * 512 + c4]);
#pragma unroll
    for (int i = 0; i < 16; ++i) {
      const float x = vs[rbase + b * 16 + i];
      acc.x = fmaf(x, w[i].x, acc.x);
      acc.y = fmaf(x, w[i].y, acc.y);
      acc.z = fmaf(x, w[i].z, acc.z);
      acc.w = fmaf(x, w[i].w, acc.w);
    }
  }
  if (half == 1) red[t & 127] = acc;
  __syncthreads();
  if (half == 0) {
    const float4 o = red[t];
    atomicAdd(&z0[c4 + 0], acc.x + o.x);
    atomicAdd(&z0[c4 + 1], acc.y + o.y);
    atomicAdd(&z0[c4 + 2], acc.z + o.z);
    atomicAdd(&z0[c4 + 3], acc.w + o.w);
  }
}

// ---------------------------------------------------------------------------
// K6a v2: z1[c] += relu(z0+lin_b)[16-row slice] @ lin1W.  32 blocks.
// ---------------------------------------------------------------------------
__global__ __launch_bounds__(256) void z1_kernel(
    const float* __restrict__ z0, const float* __restrict__ lin_b,
    const float* __restrict__ lin1W, float* __restrict__ z1) {
  __shared__ float zr[16];
  const int t = threadIdx.x;
  const int k0 = blockIdx.x * 16;
  if (t < 16) zr[t] = fmaxf(z0[k0 + t] + lin_b[k0 + t], 0.f);
  __syncthreads();
  float w[16];
#pragma unroll
  for (int i = 0; i < 16; ++i) w[i] = lin1W[(size_t)(k0 + i) * 256 + t];
  float acc = 0.f;
#pragma unroll
  for (int i = 0; i < 16; ++i) acc = fmaf(zr[i], w[i], acc);
  atomicAdd(&z1[t], acc);
}

// ---------------------------------------------------------------------------
// K6b v2 (fused): z2 = relu(relu(z1+lin1b) @ outW + outb); out = softmax(z2).
// One block, 256 threads: col = t&127, k-half = t>>7, batched 16-deep loads.
// ---------------------------------------------------------------------------
__global__ __launch_bounds__(256) void z2sm_kernel(
    const float* __restrict__ z1, const float* __restrict__ lin1b,
    const float* __restrict__ outW, const float* __restrict__ outb,
    float* __restrict__ out) {
  __shared__ float zr[256];
  __shared__ float red2[2][128];
  __shared__ float z2s[128];
  __shared__ float r[128];
  const int t = threadIdx.x;
  zr[t] = fmaxf(z1[t] + lin1b[t], 0.f);
  __syncthreads();
  const int c = t & 127;
  const int kh = t >> 7;
  float acc = 0.f;
#pragma unroll
  for (int b = 0; b < 8; ++b) {
    const int k0 = kh * 128 + b * 16;
    float w[16];
#pragma unroll
    for (int i = 0; i < 16; ++i) w[i] = outW[(size_t)(k0 + i) * 128 + c];
#pragma unroll
    for (int i = 0; i < 16; ++i) acc = fmaf(zr[k0 + i], w[i], acc);
  }
  red2[kh][c] = acc;
  __syncthreads();
  if (t < 128) {
    const float z = fmaxf(red2[0][t] + red2[1][t] + outb[t], 0.f);
    z2s[t] = z;
    r[t] = z;
  }
  __syncthreads();
  for (int off = 64; off > 0; off >>= 1) {
    if (t < off) r[t] = fmaxf(r[t], r[t + off]);
    __syncthreads();
  }
  const float mx = r[0];
  __syncthreads();
  if (t < 128) {
    const float e = expf(z2s[t] - mx);
    z2s[t] = e;
    r[t] = e;
  }
  __syncthreads();
  for (int off = 64; off > 0; off >>= 1) {
    if (t < off) r[t] += r[t + off];
    __syncthreads();
  }
  if (t < 128) out[t] = z2s[t] / r[0];
}

// ---------------------------------------------------------------------------
extern "C" void kernel_launch(void* const* d_in, const int* in_sizes, int n_in,
                              void* d_out, int out_size, void* d_ws,
                              size_t ws_size, hipStream_t stream) {
  const float* x      = (const float*)d_in[0];
  const int*   ei     = (const int*)d_in[1];
  const float* c1_W1  = (const float*)d_in[2];
  const float* c1_b1  = (const float*)d_in[3];
  const float* c1_W2  = (const float*)d_in[4];
  const float* c1_b2  = (const float*)d_in[5];
  const float* c2_W1  = (const float*)d_in[6];
  const float* c2_b1  = (const float*)d_in[7];
  const float* c2_W2  = (const float*)d_in[8];
  const float* c2_b2  = (const float*)d_in[9];
  const float* lin_W  = (const float*)d_in[10];
  const float* lin_b  = (const float*)d_in[11];
  const float* lin1_W = (const float*)d_in[12];
  const float* lin1_b = (const float*)d_in[13];
  const float* out_W  = (const float*)d_in[14];
  const float* out_b  = (const float*)d_in[15];
  float* out = (float*)d_out;

  char* wsb = (char*)d_ws;
  // Zeroed region: mask | U1 V1 U2 V2 | z0 z1   (single memset)
  unsigned int* mask = (unsigned int*)wsb;          // 2048 B
  float* U1 = (float*)(wsb + 2048);                 // 128x512 f32 each
  float* V1 = U1 + 65536;
  float* U2 = V1 + 65536;
  float* V2 = U2 + 65536;
  float* z0 = V2 + 65536;                           // 512
  float* z1 = z0 + 512;                             // 256
  const size_t zero_bytes = 2048 + 4 * 65536 * 4 + (512 + 256) * 4;
  // Non-zeroed scratch:
  float* h1 = z1 + 256;                             // 128x512 f32
  float* h2 = h1 + 65536;
  _Float16* W2t1 = (_Float16*)(h2 + 65536);         // 512x512 f16 each
  _Float16* W2t2 = W2t1 + 262144;

  hipMemsetAsync(wsb, 0, zero_bytes, stream);
  prep_kernel<<<384, 256, 0, stream>>>(ei, mask, c1_W2, c2_W2, W2t1, W2t2);
  uv_gemm3_kernel<256><<<dim3(16, 8), 256, 0, stream>>>(x, c1_W1, c1_b1, U1, V1);
  pair_mfma_kernel<<<dim3(4, 128), 256, 0, stream>>>(U1, V1, W2t1, c1_b2, mask, h1);
  uv_gemm3_kernel<512><<<dim3(16, 8), 256, 0, stream>>>(h1, c2_W1, c2_b1, U2, V2);
  pair_mfma_kernel<<<dim3(4, 128), 256, 0, stream>>>(U2, V2, W2t2, c2_b2, mask, h2);
  head_gemv_kernel<<<1024, 256, 0, stream>>>(h2, lin_W, z0);
  z1_kernel<<<32, 256, 0, stream>>>(z0, lin_b, lin1_W, z1);
  z2sm_kernel<<<1, 256, 0, stream>>>(z1, lin1_b, out_W, out_b, out);
}

// Round 5
// 314.673 us; speedup vs baseline: 1.3932x; 1.3932x over previous
//
#include <hip/hip_runtime.h>
#include <cfloat>
#include <cmath>
#include <cstdint>

#define N_NODES 128
#define F_IN    256
#define HDIM    512
#define NEDGE   524288

typedef _Float16 half8 __attribute__((ext_vector_type(8)));
typedef _Float16 half4 __attribute__((ext_vector_type(4)));
typedef float f32x4 __attribute__((ext_vector_type(4)));

// ---------------------------------------------------------------------------
// PREP (fused): blocks [0,256) build adjacency bitmask; blocks [256,384)
// convert W2 f32 [k][n] -> f16 transposed [n][k] for both layers.
// ---------------------------------------------------------------------------
__global__ __launch_bounds__(256) void prep_kernel(
    const int* __restrict__ ei, unsigned int* __restrict__ mask,
    const float* __restrict__ W2a, const float* __restrict__ W2b,
    _Float16* __restrict__ Ta, _Float16* __restrict__ Tb) {
  __shared__ __align__(16) char smem[64 * 72 * 2];
  const int t = threadIdx.x;
  if (blockIdx.x < 256) {
    unsigned int* lm = (unsigned int*)smem;
    for (int i = t; i < N_NODES * 4; i += 256) lm[i] = 0u;
    __syncthreads();
    const int base = blockIdx.x * 2048;
#pragma unroll
    for (int r = 0; r < 8; ++r) {
      const int e = base + r * 256 + t;
      const int s = ei[e];          // src  (x_j)
      const int d = ei[NEDGE + e];  // dst  (segment target)
      atomicOr(&lm[d * 4 + (s >> 5)], 1u << (s & 31));
    }
    __syncthreads();
    for (int i = t; i < N_NODES * 4; i += 256) {
      const unsigned int v = lm[i];
      if (v) atomicOr(&mask[i], v);
    }
  } else {
    const int b = blockIdx.x - 256;
    const int layer = b >> 6;
    const int rem = b & 63;
    const int kb = (rem & 7) * 64;
    const int nb = (rem >> 3) * 64;
    const float* W = layer ? W2b : W2a;
    _Float16* T = layer ? Tb : Ta;
    _Float16(*tile)[72] = (_Float16(*)[72])smem;
#pragma unroll
    for (int i = 0; i < 4; ++i) {
      const int slot = t + i * 256;
      const int kk = slot >> 4;
      const int nq = (slot & 15) * 4;
      const float4 w4 = *reinterpret_cast<const float4*>(
          &W[(size_t)(kb + kk) * HDIM + nb + nq]);
      tile[nq + 0][kk] = (_Float16)w4.x;
      tile[nq + 1][kk] = (_Float16)w4.y;
      tile[nq + 2][kk] = (_Float16)w4.z;
      tile[nq + 3][kk] = (_Float16)w4.w;
    }
    __syncthreads();
#pragma unroll
    for (int i = 0; i < 2; ++i) {
      const int slot = t + i * 256;
      const int n = slot >> 3;
      const int ko = (slot & 7) * 8;
      *reinterpret_cast<half8*>(&T[(size_t)(nb + n) * HDIM + kb + ko]) =
          *reinterpret_cast<const half8*>(&tile[n][ko]);
    }
  }
}

// ---------------------------------------------------------------------------
// K1/K3 v4: U[d,h] = A[d]@(Wtop-Wbot)+b, V[d,h] = A[d]@Wbot.
// Grid (32 h-tiles of 16, 4 K-slices) = 128 blocks. Block: 128 d x 16 h.
// Thread: tx=t&3 (4 h), ty=t>>2 (2 d rows). atomicAdd into zeroed U/V
// (contention 4 per address — pipelines fine; different addrs parallel).
// ---------------------------------------------------------------------------
template <int KK>
__global__ __launch_bounds__(256) void uv_gemm4_kernel(
    const float* __restrict__ A, const float* __restrict__ W,
    const float* __restrict__ bias, float* __restrict__ U,
    float* __restrict__ V) {
  constexpr int S = 4;
  constexpr int KS = KK / S;
  constexpr int BK = 32;
  __shared__ float As[128][BK + 1];
  __shared__ float Wd[BK][20];   // 20 floats = 80 B row: 16B-aligned for f4
  __shared__ float Wb[BK][20];
  const int t = threadIdx.x;
  const int tx = t & 3;
  const int ty = t >> 2;
  const int h0 = blockIdx.x * 16;
  const int ks0 = blockIdx.y * KS;

  float accU[2][4], accV[2][4];
#pragma unroll
  for (int i = 0; i < 2; ++i)
#pragma unroll
    for (int j = 0; j < 4; ++j) { accU[i][j] = 0.f; accV[i][j] = 0.f; }

  for (int ch = 0; ch < KS / BK; ++ch) {
    const int k0 = ks0 + ch * BK;
    __syncthreads();
    // A chunk: 128 d x 32 k (1024 float4, 4/thread)
#pragma unroll
    for (int i = 0; i < 4; ++i) {
      const int slot = t + i * 256;
      const int dd = slot >> 3, kw = (slot & 7) * 4;
      const float4 a4 =
          *reinterpret_cast<const float4*>(&A[dd * KK + k0 + kw]);
      As[dd][kw + 0] = a4.x;
      As[dd][kw + 1] = a4.y;
      As[dd][kw + 2] = a4.z;
      As[dd][kw + 3] = a4.w;
    }
    // W chunk: 32 k x 16 h top+bot (threads 0..127)
    if (t < 128) {
      const int k = t >> 2, hq = (t & 3) * 4;
      const float4 wt = *reinterpret_cast<const float4*>(
          &W[(size_t)(k0 + k) * HDIM + h0 + hq]);
      const float4 wb = *reinterpret_cast<const float4*>(
          &W[(size_t)(KK + k0 + k) * HDIM + h0 + hq]);
      *reinterpret_cast<float4*>(&Wb[k][hq]) = wb;
      float4 wd;
      wd.x = wt.x - wb.x; wd.y = wt.y - wb.y;
      wd.z = wt.z - wb.z; wd.w = wt.w - wb.w;
      *reinterpret_cast<float4*>(&Wd[k][hq]) = wd;
    }
    __syncthreads();
#pragma unroll
    for (int k = 0; k < BK; ++k) {
      float a[2];
#pragma unroll
      for (int i = 0; i < 2; ++i) a[i] = As[ty * 2 + i][k];
      const float4 wd4 = *reinterpret_cast<const float4*>(&Wd[k][tx * 4]);
      const float4 wb4 = *reinterpret_cast<const float4*>(&Wb[k][tx * 4]);
      const float wdv[4] = {wd4.x, wd4.y, wd4.z, wd4.w};
      const float wbv[4] = {wb4.x, wb4.y, wb4.z, wb4.w};
#pragma unroll
      for (int i = 0; i < 2; ++i)
#pragma unroll
        for (int j = 0; j < 4; ++j) {
          accU[i][j] = fmaf(a[i], wdv[j], accU[i][j]);
          accV[i][j] = fmaf(a[i], wbv[j], accV[i][j]);
        }
    }
  }
  const int cbase = h0 + tx * 4;
  float bb[4] = {0.f, 0.f, 0.f, 0.f};
  if (blockIdx.y == 0) {
#pragma unroll
    for (int j = 0; j < 4; ++j) bb[j] = bias[cbase + j];
  }
#pragma unroll
  for (int i = 0; i < 2; ++i) {
    const int row = ty * 2 + i;
#pragma unroll
    for (int j = 0; j < 4; ++j) {
      atomicAdd(&U[row * HDIM + cbase + j], accU[i][j] + bb[j]);
      atomicAdd(&V[row * HDIM + cbase + j], accV[i][j]);
    }
  }
}

// ---------------------------------------------------------------------------
// K2/K4: MFMA fp16 pair GEMM + fused masked max + bias + relu.
// UNCAPPED launch_bounds (R4's (256,3) cap forced VGPR<=85 -> spills).
// LDS ~41 KB -> 3 blocks/CU naturally if VGPR allows.
// ---------------------------------------------------------------------------
#define PBK 64
__global__ __launch_bounds__(256) void pair_mfma_kernel(
    const float* __restrict__ U, const float* __restrict__ V,
    const _Float16* __restrict__ W2t, const float* __restrict__ b2,
    const unsigned int* __restrict__ mask, float* __restrict__ out) {
  __shared__ _Float16 As[128][PBK + 8];
  __shared__ _Float16 Bs[128][PBK + 8];
  __shared__ float Ur[HDIM];
  __shared__ float red[4][128];
  const int t = threadIdx.x;
  const int d = blockIdx.y;
  const int c0 = blockIdx.x * 128;
  const int lane = t & 63;
  const int wid = t >> 6;
  const int l15 = lane & 15;
  const int quad = lane >> 4;

  for (int i = t; i < HDIM; i += 256) Ur[i] = U[d * HDIM + i];
  const unsigned int mwv[4] = {mask[d * 4 + 0], mask[d * 4 + 1],
                               mask[d * 4 + 2], mask[d * 4 + 3]};

  f32x4 acc[8][2];
#pragma unroll
  for (int mt = 0; mt < 8; ++mt)
#pragma unroll
    for (int nt = 0; nt < 2; ++nt) acc[mt][nt] = (f32x4)(0.f);

  for (int ch = 0; ch < HDIM / PBK; ++ch) {
    const int k0 = ch * PBK;
    __syncthreads();
#pragma unroll
    for (int i = 0; i < 8; ++i) {
      const int slot = t + i * 256;
      const int s = slot >> 4;
      const int kq = (slot & 15) * 4;
      const float4 v4 =
          *reinterpret_cast<const float4*>(&V[s * HDIM + k0 + kq]);
      const float4 u4 = *reinterpret_cast<const float4*>(&Ur[k0 + kq]);
      half4 h;
      h.x = (_Float16)fmaxf(u4.x + v4.x, 0.f);
      h.y = (_Float16)fmaxf(u4.y + v4.y, 0.f);
      h.z = (_Float16)fmaxf(u4.z + v4.z, 0.f);
      h.w = (_Float16)fmaxf(u4.w + v4.w, 0.f);
      *reinterpret_cast<half4*>(&As[s][kq]) = h;
    }
#pragma unroll
    for (int i = 0; i < 4; ++i) {
      const int slot = t + i * 256;
      const int n = slot >> 3;
      const int ko = (slot & 7) * 8;
      *reinterpret_cast<half8*>(&Bs[n][ko]) = *reinterpret_cast<const half8*>(
          &W2t[(size_t)(c0 + n) * HDIM + k0 + ko]);
    }
    __syncthreads();
#pragma unroll
    for (int ks = 0; ks < PBK / 32; ++ks) {
      half8 bf[2];
#pragma unroll
      for (int nt = 0; nt < 2; ++nt)
        bf[nt] = *reinterpret_cast<const half8*>(
            &Bs[wid * 32 + nt * 16 + l15][ks * 32 + quad * 8]);
#pragma unroll
      for (int mt = 0; mt < 8; ++mt) {
        const half8 af = *reinterpret_cast<const half8*>(
            &As[mt * 16 + l15][ks * 32 + quad * 8]);
#pragma unroll
        for (int nt = 0; nt < 2; ++nt)
          acc[mt][nt] = __builtin_amdgcn_mfma_f32_16x16x32_f16(
              af, bf[nt], acc[mt][nt], 0, 0, 0);
      }
    }
  }
  __syncthreads();
#pragma unroll
  for (int nt = 0; nt < 2; ++nt) {
    float pm = -FLT_MAX;
#pragma unroll
    for (int mt = 0; mt < 8; ++mt) {
      const int sbase = mt * 16 + quad * 4;
      const unsigned int w = mwv[sbase >> 5] >> (sbase & 31);
#pragma unroll
      for (int r = 0; r < 4; ++r)
        if ((w >> r) & 1u) pm = fmaxf(pm, acc[mt][nt][r]);
    }
    red[quad][wid * 32 + nt * 16 + l15] = pm;
  }
  __syncthreads();
  if (t < 128) {
    const float m = fmaxf(fmaxf(red[0][t], red[1][t]),
                          fmaxf(red[2][t], red[3][t]));
    out[d * HDIM + c0 + t] = fmaxf(m + b2[c0 + t], 0.f);
  }
}

// ---------------------------------------------------------------------------
// K5 v4: z0r[b%8][j] += sum_i v[i]*W[i,j].
// 512 blocks x 128 rows. Wave w owns rows [w*32,+32) at FULL row width:
// lane l covers cols [8l, 8l+8) -> each wave streams a CONTIGUOUS 64 KB
// region (2 KB per row, rows sequential). 8-row batches = 16 float4 in
// flight. Atomics: 8 XCD replicas -> contention 64/address, XCD-local L2.
// ---------------------------------------------------------------------------
__global__ __launch_bounds__(256) void head_gemv4_kernel(
    const float* __restrict__ v, const float* __restrict__ W,
    float* __restrict__ z0r) {
  __shared__ float vs[128];
  __shared__ float red[4][512];
  const int t = threadIdx.x;
  const int b = blockIdx.x;
  const int row0 = b * 128;
  if (t < 128) vs[t] = v[row0 + t];
  __syncthreads();
  const int w = t >> 6;
  const int l = t & 63;
  const float* Wp = W + (size_t)row0 * 512 + l * 8;
  float4 accA = make_float4(0.f, 0.f, 0.f, 0.f);
  float4 accB = make_float4(0.f, 0.f, 0.f, 0.f);
#pragma unroll
  for (int bb = 0; bb < 4; ++bb) {
    const int r0 = w * 32 + bb * 8;
    float4 wa[8], wb[8];
#pragma unroll
    for (int i = 0; i < 8; ++i) {
      const float* p = Wp + (size_t)(r0 + i) * 512;
      wa[i] = *reinterpret_cast<const float4*>(p);
      wb[i] = *reinterpret_cast<const float4*>(p + 4);
    }
#pragma unroll
    for (int i = 0; i < 8; ++i) {
      const float x = vs[r0 + i];
      accA.x = fmaf(x, wa[i].x, accA.x);
      accA.y = fmaf(x, wa[i].y, accA.y);
      accA.z = fmaf(x, wa[i].z, accA.z);
      accA.w = fmaf(x, wa[i].w, accA.w);
      accB.x = fmaf(x, wb[i].x, accB.x);
      accB.y = fmaf(x, wb[i].y, accB.y);
      accB.z = fmaf(x, wb[i].z, accB.z);
      accB.w = fmaf(x, wb[i].w, accB.w);
    }
  }
  *reinterpret_cast<float4*>(&red[w][l * 8]) = accA;
  *reinterpret_cast<float4*>(&red[w][l * 8 + 4]) = accB;
  __syncthreads();
  // 256 threads: cols t and t+256; one atomic each into this block's replica.
  float* zr = z0r + (size_t)(b & 7) * 512;
  const float s0 = red[0][t] + red[1][t] + red[2][t] + red[3][t];
  const int c2 = t + 256;
  const float s1 = red[0][c2] + red[1][c2] + red[2][c2] + red[3][c2];
  atomicAdd(&zr[t], s0);
  atomicAdd(&zr[c2], s1);
}

// ---------------------------------------------------------------------------
// K6 (fused tail): z0 = sum_8 z0r; z1 = relu(relu(z0+b)@lin1W + b1);
// z2 = relu(z1@outW + b2); out = softmax(z2). One block, 512 threads.
// ---------------------------------------------------------------------------
__global__ __launch_bounds__(512) void head_tail_kernel(
    const float* __restrict__ z0r, const float* __restrict__ lin_b,
    const float* __restrict__ lin1W, const float* __restrict__ lin1b,
    const float* __restrict__ outW, const float* __restrict__ outb,
    float* __restrict__ out) {
  __shared__ float zr[512];
  __shared__ float r1[2][256];
  __shared__ float z1s[256];
  __shared__ float r2[4][128];
  __shared__ float z2s[128];
  __shared__ float rr[128];
  const int t = threadIdx.x;
  {
    float s = 0.f;
#pragma unroll
    for (int r = 0; r < 8; ++r) s += z0r[r * 512 + t];
    zr[t] = fmaxf(s + lin_b[t], 0.f);
  }
  __syncthreads();
  // z1: col = t&255, k-half = t>>8 (256 k each), 16-deep batches
  {
    const int c = t & 255;
    const int kh = t >> 8;
    float acc = 0.f;
#pragma unroll
    for (int b2 = 0; b2 < 16; ++b2) {
      const int k0 = kh * 256 + b2 * 16;
      float wv[16];
#pragma unroll
      for (int i = 0; i < 16; ++i) wv[i] = lin1W[(size_t)(k0 + i) * 256 + c];
#pragma unroll
      for (int i = 0; i < 16; ++i) acc = fmaf(zr[k0 + i], wv[i], acc);
    }
    r1[kh][c] = acc;
  }
  __syncthreads();
  if (t < 256) z1s[t] = fmaxf(r1[0][t] + r1[1][t] + lin1b[t], 0.f);
  __syncthreads();
  // z2: col = t&127, k-quarter = t>>7 (64 k each)
  {
    const int c = t & 127;
    const int kq = t >> 7;
    float acc = 0.f;
#pragma unroll
    for (int b2 = 0; b2 < 4; ++b2) {
      const int k0 = kq * 64 + b2 * 16;
      float wv[16];
#pragma unroll
      for (int i = 0; i < 16; ++i) wv[i] = outW[(size_t)(k0 + i) * 128 + c];
#pragma unroll
      for (int i = 0; i < 16; ++i) acc = fmaf(z1s[k0 + i], wv[i], acc);
    }
    r2[kq][c] = acc;
  }
  __syncthreads();
  if (t < 128) {
    const float z =
        fmaxf(r2[0][t] + r2[1][t] + r2[2][t] + r2[3][t] + outb[t], 0.f);
    z2s[t] = z;
    rr[t] = z;
  }
  __syncthreads();
  for (int off = 64; off > 0; off >>= 1) {
    if (t < off) rr[t] = fmaxf(rr[t], rr[t + off]);
    __syncthreads();
  }
  const float mx = rr[0];
  __syncthreads();
  if (t < 128) {
    const float e = expf(z2s[t] - mx);
    z2s[t] = e;
    rr[t] = e;
  }
  __syncthreads();
  for (int off = 64; off > 0; off >>= 1) {
    if (t < off) rr[t] += rr[t + off];
    __syncthreads();
  }
  if (t < 128) out[t] = z2s[t] / rr[0];
}

// ---------------------------------------------------------------------------
extern "C" void kernel_launch(void* const* d_in, const int* in_sizes, int n_in,
                              void* d_out, int out_size, void* d_ws,
                              size_t ws_size, hipStream_t stream) {
  const float* x      = (const float*)d_in[0];
  const int*   ei     = (const int*)d_in[1];
  const float* c1_W1  = (const float*)d_in[2];
  const float* c1_b1  = (const float*)d_in[3];
  const float* c1_W2  = (const float*)d_in[4];
  const float* c1_b2  = (const float*)d_in[5];
  const float* c2_W1  = (const float*)d_in[6];
  const float* c2_b1  = (const float*)d_in[7];
  const float* c2_W2  = (const float*)d_in[8];
  const float* c2_b2  = (const float*)d_in[9];
  const float* lin_W  = (const float*)d_in[10];
  const float* lin_b  = (const float*)d_in[11];
  const float* lin1_W = (const float*)d_in[12];
  const float* lin1_b = (const float*)d_in[13];
  const float* out_W  = (const float*)d_in[14];
  const float* out_b  = (const float*)d_in[15];
  float* out = (float*)d_out;

  char* wsb = (char*)d_ws;
  // Zeroed region: mask | z0r[8][512] | U1 V1 U2 V2   (single memset)
  unsigned int* mask = (unsigned int*)wsb;          // 2048 B
  float* z0r = (float*)(wsb + 2048);                // 8*512 floats
  float* U1 = z0r + 4096;                           // 128x512 f32 each
  float* V1 = U1 + 65536;
  float* U2 = V1 + 65536;
  float* V2 = U2 + 65536;
  const size_t zero_bytes = 2048 + 4096 * 4 + 4 * 65536 * 4;
  // Non-zeroed scratch:
  float* h1 = V2 + 65536;                           // 128x512 f32
  float* h2 = h1 + 65536;
  _Float16* W2t1 = (_Float16*)(h2 + 65536);         // 512x512 f16 each
  _Float16* W2t2 = W2t1 + 262144;

  hipMemsetAsync(wsb, 0, zero_bytes, stream);
  prep_kernel<<<384, 256, 0, stream>>>(ei, mask, c1_W2, c2_W2, W2t1, W2t2);
  uv_gemm4_kernel<256><<<dim3(32, 4), 256, 0, stream>>>(x, c1_W1, c1_b1, U1, V1);
  pair_mfma_kernel<<<dim3(4, 128), 256, 0, stream>>>(U1, V1, W2t1, c1_b2, mask, h1);
  uv_gemm4_kernel<512><<<dim3(32, 4), 256, 0, stream>>>(h1, c2_W1, c2_b1, U2, V2);
  pair_mfma_kernel<<<dim3(4, 128), 256, 0, stream>>>(U2, V2, W2t2, c2_b2, mask, h2);
  head_gemv4_kernel<<<512, 256, 0, stream>>>(h2, lin_W, z0r);
  head_tail_kernel<<<1, 512, 0, stream>>>(z0r, lin_b, lin1_W, lin1_b, out_W,
                                          out_b, out);
}